// Round 8
// baseline (440.085 us; speedup 1.0000x reference)
//
#include <hip/hip_runtime.h>
#include <hip/hip_bf16.h>

typedef unsigned short u16;
typedef unsigned int u32;

typedef short bf16x8 __attribute__((ext_vector_type(8)));
typedef float f32x4 __attribute__((ext_vector_type(4)));

__device__ __forceinline__ u16 f2bf(float f) {
    union { float f; u32 u; } v; v.f = f;
    u32 u = v.u;
    return (u16)((u + 0x7fffu + ((u >> 16) & 1u)) >> 16);
}
__device__ __forceinline__ float bf2f(u16 b) {
    union { u32 u; float f; } v; v.u = ((u32)b) << 16;
    return v.f;
}

#define MFMA_BF16 __builtin_amdgcn_mfma_f32_16x16x32_bf16

// ---------------------------------------------------------------------------
// QKV GEMM: C = A @ B^T. A[32768,512] bf16, B = wqkvT slice [512,512] bf16.
// 128x128 tile, 4 waves. NO LDS: A and B fragments loaded per-lane from
// global (L1/L2 line-reuse: each 128B line touched 8x within unroll window).
// Barrier-free K-loop -> compiler software-pipelines the loads.
// ---------------------------------------------------------------------------
__global__ __launch_bounds__(256, 3) void qkv_k(
    const u16* __restrict__ A, const u16* __restrict__ B, u16* __restrict__ C)
{
    const int tid  = threadIdx.x;
    const int lane = tid & 63;
    const int wave = tid >> 6;
    const int wm = (wave >> 1) * 64, wn = (wave & 1) * 64;
    const int row0 = blockIdx.x * 128;
    const int col0 = blockIdx.y * 128;
    const u16* Bb = B + (size_t)blockIdx.z * 262144;
    u16* Cb = C + (size_t)blockIdx.z * 16777216;
    const int l15 = lane & 15, l4 = lane >> 4;

    const u16* Arow = A + (size_t)(row0 + wm + l15) * 512 + l4 * 8;
    const u16* Brow = Bb + (size_t)(col0 + wn + l15) * 512 + l4 * 8;

    f32x4 acc[4][4] = {};

    #pragma unroll 4
    for (int t = 0; t < 16; ++t) {
        bf16x8 a[4], b[4];
        #pragma unroll
        for (int m = 0; m < 4; ++m)
            a[m] = *(const bf16x8*)(Arow + (size_t)m * 16 * 512 + t * 32);
        #pragma unroll
        for (int n = 0; n < 4; ++n)
            b[n] = *(const bf16x8*)(Brow + (size_t)n * 16 * 512 + t * 32);
        #pragma unroll
        for (int m = 0; m < 4; ++m)
            #pragma unroll
            for (int n = 0; n < 4; ++n)
                acc[m][n] = MFMA_BF16(a[m], b[n], acc[m][n], 0, 0, 0);
    }

    #pragma unroll
    for (int m = 0; m < 4; ++m)
        #pragma unroll
        for (int n = 0; n < 4; ++n)
            #pragma unroll
            for (int r = 0; r < 4; ++r)
                Cb[(size_t)(row0 + wm + m * 16 + l4 * 4 + r) * 512 + col0 + wn + n * 16 + l15]
                    = f2bf(acc[m][n][r]);
}

// ---------------------------------------------------------------------------
// fused back-half helpers
// ---------------------------------------------------------------------------
// W tile 64x256 bf16 in LDS, chunk-XOR swizzle within 8-chunk groups
__device__ __forceinline__ int wswz(int row, int chunk) {
    return (chunk & 24) | ((chunk ^ row) & 7);
}
__device__ __forceinline__ bf16x8 rdW(const u16* W, int row, int chunk) {
    return *(const bf16x8*)&W[row * 256 + wswz(row, chunk) * 8];
}
__device__ __forceinline__ void wrW(u16* W, int row, int col, u16 v) {
    W[row * 256 + wswz(row, col >> 3) * 8 + (col & 7)] = v;
}

// dst (+)= Wlds(64x256) @ Bg^T(256-rows x 256-K), K=256, BK=32, barrier-free.
// A-frags: ds_read from W. B-frags: per-lane 16B direct from global (L2-hot).
template<bool INIT>
__device__ __forceinline__ void gemm_WB(
    f32x4 (&dst)[4][4], const u16* __restrict__ Wlds, const u16* __restrict__ Bg,
    int ldb, int wn, int l15, int l4)
{
    if constexpr (INIT)
        #pragma unroll
        for (int m = 0; m < 4; ++m)
            #pragma unroll
            for (int n = 0; n < 4; ++n) dst[m][n] = f32x4{0.f, 0.f, 0.f, 0.f};
    const u16* Brow = Bg + (size_t)(wn + l15) * ldb + l4 * 8;
    #pragma unroll 4
    for (int t = 0; t < 8; ++t) {
        bf16x8 a[4], b[4];
        #pragma unroll
        for (int m = 0; m < 4; ++m)
            a[m] = rdW(Wlds, m * 16 + l15, t * 4 + l4);
        #pragma unroll
        for (int n = 0; n < 4; ++n)
            b[n] = *(const bf16x8*)(Brow + (size_t)n * 16 * ldb + t * 32);
        #pragma unroll
        for (int m = 0; m < 4; ++m)
            #pragma unroll
            for (int n = 0; n < 4; ++n)
                dst[m][n] = MFMA_BF16(a[m], b[n], dst[m][n], 0, 0, 0);
    }
}

// in-place row softmax; rows m*16+l4*4+rr (64 rows), cols = 4 waves x 64
__device__ __forceinline__ void row_softmax(
    f32x4 (&val)[4][4], float (&red)[64][4], int wid, int l15, int l4)
{
    float rm[4][4];
    #pragma unroll
    for (int m = 0; m < 4; ++m)
        #pragma unroll
        for (int rr = 0; rr < 4; ++rr) {
            float x = fmaxf(fmaxf(val[m][0][rr], val[m][1][rr]),
                            fmaxf(val[m][2][rr], val[m][3][rr]));
            #pragma unroll
            for (int o = 1; o < 16; o <<= 1) x = fmaxf(x, __shfl_xor(x, o, 64));
            rm[m][rr] = x;
        }
    if (l15 == 0)
        #pragma unroll
        for (int m = 0; m < 4; ++m)
            #pragma unroll
            for (int rr = 0; rr < 4; ++rr)
                red[m * 16 + l4 * 4 + rr][wid] = rm[m][rr];
    __syncthreads();
    #pragma unroll
    for (int m = 0; m < 4; ++m)
        #pragma unroll
        for (int rr = 0; rr < 4; ++rr) {
            float4 rv = *(const float4*)&red[m * 16 + l4 * 4 + rr][0];
            rm[m][rr] = fmaxf(fmaxf(rv.x, rv.y), fmaxf(rv.z, rv.w));
        }
    __syncthreads();
    float rs[4][4];
    #pragma unroll
    for (int m = 0; m < 4; ++m)
        #pragma unroll
        for (int rr = 0; rr < 4; ++rr) {
            float s = 0.f;
            #pragma unroll
            for (int n = 0; n < 4; ++n) {
                float e = __expf(val[m][n][rr] - rm[m][rr]);
                val[m][n][rr] = e;
                s += e;
            }
            #pragma unroll
            for (int o = 1; o < 16; o <<= 1) s += __shfl_xor(s, o, 64);
            rs[m][rr] = s;
        }
    if (l15 == 0)
        #pragma unroll
        for (int m = 0; m < 4; ++m)
            #pragma unroll
            for (int rr = 0; rr < 4; ++rr)
                red[m * 16 + l4 * 4 + rr][wid] = rs[m][rr];
    __syncthreads();
    #pragma unroll
    for (int m = 0; m < 4; ++m)
        #pragma unroll
        for (int rr = 0; rr < 4; ++rr) {
            float4 rv = *(const float4*)&red[m * 16 + l4 * 4 + rr][0];
            float inv = 1.f / (rv.x + rv.y + rv.z + rv.w);
            #pragma unroll
            for (int n = 0; n < 4; ++n) val[m][n][rr] *= inv;
        }
    __syncthreads();
}

// ---------------------------------------------------------------------------
// Megakernel stages 2..8. 64-row tile, grid(4,128), 256 thr.
// LDS = Wa(32K)+Wb(32K)+red+wr ~= 65.3KB -> 2 blocks/CU. All GEMM K-loops
// barrier-free (B direct from L2); barriers only at W-tile handoffs.
// ---------------------------------------------------------------------------
__global__ __launch_bounds__(256, 2) void fused_k(
    const u16* __restrict__ qb, const u16* __restrict__ kb, const u16* __restrict__ vT,
    const u16* __restrict__ w1T, const u16* __restrict__ woT,
    const float* __restrict__ pos, const float* __restrict__ b1v,
    const float* __restrict__ w2v, const float* __restrict__ b2v,
    const float* __restrict__ bov, float* __restrict__ out)
{
    __shared__ u16 Wa[64 * 256];     // attnw -> attn2 -> av1
    __shared__ u16 Wb[64 * 256];     // av0
    __shared__ float red[64][4];
    __shared__ float wr[64];

    const int tid  = threadIdx.x;
    const int lane = tid & 63;
    const int wid  = tid >> 6;                 // N quarter
    const int wn   = wid * 64;
    const int l15 = lane & 15, l4 = lane >> 4;

    // XCD-aware bijective swizzle (512 blocks = 8 XCDs x 64)
    int hw = blockIdx.x + (blockIdx.y << 2);
    int wg = ((hw & 7) << 6) | (hw >> 3);
    const int row0 = (wg & 3) * 64;
    const int z    = wg >> 2;

    const u16* q = qb + (size_t)z * 131072 + (size_t)row0 * 512;
    const u16* k = kb + (size_t)z * 131072;
    const u16* v = vT + (size_t)z * 131072;
    const float* posb = pos + (size_t)(z & 15) * 65536 + (size_t)row0 * 256;
    const float b2s = b2v[0];

    f32x4 sa[4][4] = {};
    f32x4 acc[4][4];

    // ---- P1: S = q @ k^T (K=512), barrier-free, direct loads ----
    {
        const u16* qrow = q + (size_t)l15 * 512 + l4 * 8;
        const u16* krow = k + (size_t)(wn + l15) * 512 + l4 * 8;
        #pragma unroll 4
        for (int t = 0; t < 16; ++t) {
            bf16x8 a[4], b[4];
            #pragma unroll
            for (int m = 0; m < 4; ++m)
                a[m] = *(const bf16x8*)(qrow + (size_t)m * 16 * 512 + t * 32);
            #pragma unroll
            for (int n = 0; n < 4; ++n)
                b[n] = *(const bf16x8*)(krow + (size_t)n * 16 * 512 + t * 32);
            #pragma unroll
            for (int m = 0; m < 4; ++m)
                #pragma unroll
                for (int n = 0; n < 4; ++n)
                    sa[m][n] = MFMA_BF16(a[m], b[n], sa[m][n], 0, 0, 0);
        }
    }

    // ---- P2: softmax #1 ; Wa = bf16(attn + pos) ----
    #pragma unroll
    for (int m = 0; m < 4; ++m)
        #pragma unroll
        for (int n = 0; n < 4; ++n) sa[m][n] *= 0.125f;
    row_softmax(sa, red, wid, l15, l4);
    #pragma unroll
    for (int m = 0; m < 4; ++m)
        #pragma unroll
        for (int rr = 0; rr < 4; ++rr) {
            int row = m * 16 + l4 * 4 + rr;
            #pragma unroll
            for (int n = 0; n < 4; ++n) {
                int col = wn + n * 16 + l15;
                wrW(Wa, row, col, f2bf(sa[m][n][rr] + posb[row * 256 + col]));
            }
        }
    __syncthreads();

    // ---- P3: h = relu(attnw @ w1 + b1); wrow = h . w2 + b2 ----
    float b1c[4], w2c[4];
    #pragma unroll
    for (int n = 0; n < 4; ++n) {
        int col = wn + n * 16 + l15;
        b1c[n] = b1v[col];
        w2c[n] = w2v[col];
    }
    gemm_WB<true>(acc, Wa, w1T, 256, wn, l15, l4);
    {
        float part[4][4];
        #pragma unroll
        for (int m = 0; m < 4; ++m)
            #pragma unroll
            for (int rr = 0; rr < 4; ++rr) {
                float p = 0.f;
                #pragma unroll
                for (int n = 0; n < 4; ++n)
                    p += fmaxf(acc[m][n][rr] + b1c[n], 0.f) * w2c[n];
                #pragma unroll
                for (int o = 1; o < 16; o <<= 1) p += __shfl_xor(p, o, 64);
                part[m][rr] = p;
            }
        if (l15 == 0)
            #pragma unroll
            for (int m = 0; m < 4; ++m)
                #pragma unroll
                for (int rr = 0; rr < 4; ++rr)
                    red[m * 16 + l4 * 4 + rr][wid] = part[m][rr];
        __syncthreads();
        if (wid == 0 && l15 == 0)
            #pragma unroll
            for (int m = 0; m < 4; ++m)
                #pragma unroll
                for (int rr = 0; rr < 4; ++rr) {
                    int row = m * 16 + l4 * 4 + rr;
                    float4 rv = *(const float4*)&red[row][0];
                    wr[row] = rv.x + rv.y + rv.z + rv.w + b2s;
                }
        __syncthreads();
    }

    // ---- P4: attn2 = softmax(attn * gaussian(wrow)); Wa = bf16(attn2) ----
    #pragma unroll
    for (int m = 0; m < 4; ++m)
        #pragma unroll
        for (int rr = 0; rr < 4; ++rr) {
            int row = m * 16 + l4 * 4 + rr;
            float wv = wr[row];
            float idn = 1.f / (2.f * wv * wv + 1e-6f);
            int rg = row0 + row;
            #pragma unroll
            for (int n = 0; n < 4; ++n) {
                float d = (float)(wn + n * 16 + l15 - rg);
                sa[m][n][rr] *= __expf(-d * d * idn);
            }
        }
    row_softmax(sa, red, wid, l15, l4);
    #pragma unroll
    for (int m = 0; m < 4; ++m)
        #pragma unroll
        for (int rr = 0; rr < 4; ++rr) {
            int row = m * 16 + l4 * 4 + rr;
            #pragma unroll
            for (int n = 0; n < 4; ++n)
                wrW(Wa, row, wn + n * 16 + l15, f2bf(sa[m][n][rr]));
        }
    __syncthreads();

    // ---- P5: av = attn2 @ v; av0 -> Wb, av1 -> Wa ----
    gemm_WB<true>(acc, Wa, v, 256, wn, l15, l4);           // av0 (e=0..255)
    #pragma unroll
    for (int m = 0; m < 4; ++m)
        #pragma unroll
        for (int rr = 0; rr < 4; ++rr) {
            int row = m * 16 + l4 * 4 + rr;
            #pragma unroll
            for (int n = 0; n < 4; ++n)
                wrW(Wb, row, wn + n * 16 + l15, f2bf(acc[m][n][rr]));
        }
    gemm_WB<true>(acc, Wa, v + 65536, 256, wn, l15, l4);   // av1 (e=256..511)
    __syncthreads();   // all attn2 reads done before overwrite
    #pragma unroll
    for (int m = 0; m < 4; ++m)
        #pragma unroll
        for (int rr = 0; rr < 4; ++rr) {
            int row = m * 16 + l4 * 4 + rr;
            #pragma unroll
            for (int n = 0; n < 4; ++n)
                wrW(Wa, row, wn + n * 16 + l15, f2bf(acc[m][n][rr]));
        }
    __syncthreads();   // Wa=av1, Wb=av0 ready

    // ---- P6: out = av @ w_out + b_out (per 256-col half, K-split) ----
    for (int nh = 0; nh < 2; ++nh) {
        f32x4 o[4][4];
        gemm_WB<true >(o, Wb, woT + (size_t)nh * 131072,       512, wn, l15, l4);
        gemm_WB<false>(o, Wa, woT + (size_t)nh * 131072 + 256, 512, wn, l15, l4);
        float boc[4];
        #pragma unroll
        for (int n = 0; n < 4; ++n) boc[n] = bov[nh * 256 + wn + n * 16 + l15];
        #pragma unroll
        for (int m = 0; m < 4; ++m)
            #pragma unroll
            for (int rr = 0; rr < 4; ++rr) {
                int row = row0 + m * 16 + l4 * 4 + rr;
                size_t ob = ((size_t)z * 256 + row) * 512 + nh * 256;
                #pragma unroll
                for (int n = 0; n < 4; ++n)
                    out[ob + wn + n * 16 + l15] = o[m][n][rr] + boc[n];
            }
    }
}

// ---------------------------------------------------------------------------
// fp32 [R][C] -> bf16 [C][R] (weights)
__global__ __launch_bounds__(256) void trans_f2b_k(
    const float* __restrict__ in, u16* __restrict__ out, int R, int C)
{
    __shared__ u16 t[64][80];
    const int bx = blockIdx.x, by = blockIdx.y;
    const int tid = threadIdx.x;
    const int r = tid >> 2, c16 = (tid & 3) * 16;
    const float* ip = in + (size_t)(by * 64 + r) * C + bx * 64 + c16;
    #pragma unroll
    for (int j = 0; j < 4; ++j) {
        float4 vv = *(const float4*)(ip + j * 4);
        t[r][c16 + j * 4 + 0] = f2bf(vv.x);
        t[r][c16 + j * 4 + 1] = f2bf(vv.y);
        t[r][c16 + j * 4 + 2] = f2bf(vv.z);
        t[r][c16 + j * 4 + 3] = f2bf(vv.w);
    }
    __syncthreads();
    const int orow = tid >> 2, oc = (tid & 3) * 16;
    u16 o[16];
    #pragma unroll
    for (int j = 0; j < 16; ++j) o[j] = t[oc + j][orow];
    u16* op = out + (size_t)(bx * 64 + orow) * R + by * 64 + oc;
    *(int4*)op       = *(const int4*)&o[0];
    *(int4*)(op + 8) = *(const int4*)&o[8];
}

// bf16 [R][C] -> bf16 [C][R], batched (v -> vT)
__global__ __launch_bounds__(256) void trans_b2b_k(
    const u16* __restrict__ in, u16* __restrict__ out,
    int ldin, int R, long sIn, long sOut)
{
    __shared__ u16 t[64][80];
    const int bx = blockIdx.x, by = blockIdx.y;
    const long zz = blockIdx.z;
    const u16* ip = in + zz * sIn;
    u16* op = out + zz * sOut;
    const int tid = threadIdx.x;
    const int r = tid >> 2, c16 = (tid & 3) * 16;
    const u16* src = ip + (size_t)(by * 64 + r) * ldin + bx * 64 + c16;
    *(int4*)&t[r][c16]     = *(const int4*)src;
    *(int4*)&t[r][c16 + 8] = *(const int4*)(src + 8);
    __syncthreads();
    const int orow = tid >> 2, oc = (tid & 3) * 16;
    u16 o[16];
    #pragma unroll
    for (int j = 0; j < 16; ++j) o[j] = t[oc + j][orow];
    u16* dst = op + (size_t)(bx * 64 + orow) * R + by * 64 + oc;
    *(int4*)dst       = *(const int4*)&o[0];
    *(int4*)(dst + 8) = *(const int4*)&o[8];
}

// fp32 -> bf16 flat convert
__global__ __launch_bounds__(256) void conv_b_k(
    const float* __restrict__ in, u16* __restrict__ out, int n8)
{
    int i = blockIdx.x * 256 + threadIdx.x;
    if (i >= n8) return;
    float4 a = ((const float4*)in)[i * 2], b = ((const float4*)in)[i * 2 + 1];
    u16 o[8] = { f2bf(a.x), f2bf(a.y), f2bf(a.z), f2bf(a.w),
                 f2bf(b.x), f2bf(b.y), f2bf(b.z), f2bf(b.w) };
    ((int4*)out)[i] = *(const int4*)o;
}

// ---------------------------------------------------------------------------
extern "C" void kernel_launch(void* const* d_in, const int* in_sizes, int n_in,
                              void* d_out, int out_size, void* d_ws, size_t ws_size,
                              hipStream_t stream) {
    const float* x     = (const float*)d_in[0];
    const float* w_qkv = (const float*)d_in[1];
    const float* pos   = (const float*)d_in[2];
    const float* w1    = (const float*)d_in[3];
    const float* b1    = (const float*)d_in[4];
    const float* w2    = (const float*)d_in[5];
    const float* b2    = (const float*)d_in[6];
    const float* w_out = (const float*)d_in[7];
    const float* b_out = (const float*)d_in[8];
    float* out = (float*)d_out;
    char* ws = (char*)d_ws;

    u16* xb    = (u16*)(ws);                      // [0,32M)
    u16* vT    = (u16*)(ws);                      // [0,32M) after xb dead
    u16* qkvb  = (u16*)(ws + 33554432);           // [32,128M) q|k|v
    u16* wqkvT = (u16*)(ws + 134217728);
    u16* w1T   = (u16*)(ws + 135790592);
    u16* woT   = (u16*)(ws + 135921664);
    if (ws_size < (size_t)136445952) return;

    u16* qb = qkvb;
    u16* kb = qkvb + 16777216;
    u16* vb = qkvb + 33554432;

    dim3 blk(256);

    conv_b_k<<<dim3(8192), blk, 0, stream>>>(x, xb, 2097152);
    trans_f2b_k<<<dim3(24, 8), blk, 0, stream>>>(w_qkv, wqkvT, 512, 1536);
    trans_f2b_k<<<dim3(4, 4), blk, 0, stream>>>(w1, w1T, 256, 256);
    trans_f2b_k<<<dim3(8, 8), blk, 0, stream>>>(w_out, woT, 512, 512);

    qkv_k<<<dim3(256, 4, 3), blk, 0, stream>>>(xb, wqkvT, qkvb);

    trans_b2b_k<<<dim3(8, 4, 128), blk, 0, stream>>>(vb, vT, 512, 256, 131072L, 131072L);

    fused_k<<<dim3(4, 128), blk, 0, stream>>>(
        qb, kb, vT, w1T, woT, pos, b1, w2, b2, b_out, out);
}